// Round 11
// baseline (131.097 us; speedup 1.0000x reference)
//
#include <hip/hip_runtime.h>
#include <math.h>

#define B_    8
#define NIN_  4096
#define P_    1024
#define K_    16
#define F_    64
#define CH_   67      // 3 + F
#define CPF_  64
#define CIN_  128
#define C_    128

// ---- ws float-offset layout ----
#define S_PF1  0
#define SH_PF1 64
#define S_PF2  128
#define SH_PF2 192
#define S_C1   256
#define SH_C1  512
#define S_C2   768
#define SH_C2  1024
#define S_C3   1280
#define SH_C3  1536
#define S_F    1792
#define SH_F   1920
#define M_OFF  2048     // fused pf matrix 3x64
#define C0_OFF 2240     // fused pf bias 64

// byte offsets in ws
#define WS_PTS_OFF  16384

typedef float f2 __attribute__((ext_vector_type(2)));
typedef float f4 __attribute__((ext_vector_type(4)));

__device__ __forceinline__ float rlf(float x, int l) {
    return __int_as_float(__builtin_amdgcn_readlane(__float_as_int(x), l));
}
__device__ __forceinline__ int rli(int x, int l) {
    return __builtin_amdgcn_readlane(x, l);
}
__device__ __forceinline__ float eluf(float z) {
    return z > 0.f ? z : (__expf(z) - 1.0f);
}
// whole-wave shift-right-by-1 via DPP (VALU). lane0 receives -inf.
__device__ __forceinline__ float dpp_shr1_ninf(float x) {
    return __int_as_float(__builtin_amdgcn_update_dpp(
        (int)0xFF800000, __float_as_int(x), 0x138, 0xF, 0xF, false));
}
// lane0 keeps old value (don't-care for index path)
__device__ __forceinline__ int dpp_shr1_i(int x) {
    return __builtin_amdgcn_update_dpp(x, x, 0x138, 0xF, 0xF, false);
}

// ---------------------------------------------------------------------------
// Kernel 0 (fused prep): blocks 0..127 pack xyz + 0.5*|p|^2 into float4;
// block 128 folds BN params and collapses pf1+pf2 into a 3->64 affine.
// ---------------------------------------------------------------------------
__global__ __launch_bounds__(256) void prep_kernel(
    const float* __restrict__ inp, float4* __restrict__ pts,
    const float* __restrict__ bn_pf1, const float* __restrict__ bn_pf2,
    const float* __restrict__ bn_c1,  const float* __restrict__ bn_c2,
    const float* __restrict__ bn_c3,  const float* __restrict__ bn_f,
    const float* __restrict__ Wpf1,   const float* __restrict__ bpf1,
    const float* __restrict__ Wpf2,   const float* __restrict__ bpf2,
    float* __restrict__ wsf) {
    const int tid = threadIdx.x;
    if (blockIdx.x < 128) {
        int i = blockIdx.x * 256 + tid;
        const float* r = inp + (size_t)i * CH_;
        float x = r[0], y = r[1], z = r[2];
        float pp = __fadd_rn(__fadd_rn(__fmul_rn(x, x), __fmul_rn(y, y)),
                             __fmul_rn(z, z));
        pts[i] = make_float4(x, y, z, __fmul_rn(0.5f, pp));
        return;
    }
#pragma unroll
    for (int it = 0; it < 4; ++it) {
        int t = it * 256 + tid;
        const float* src; int nch, c, so, sho;
        if (t < 64)       { src = bn_pf1; nch = 64;  c = t;        so = S_PF1; sho = SH_PF1; }
        else if (t < 128) { src = bn_pf2; nch = 64;  c = t - 64;   so = S_PF2; sho = SH_PF2; }
        else if (t < 384) { src = bn_c1;  nch = 256; c = t - 128;  so = S_C1;  sho = SH_C1; }
        else if (t < 640) { src = bn_c2;  nch = 256; c = t - 384;  so = S_C2;  sho = SH_C2; }
        else if (t < 896) { src = bn_c3;  nch = 256; c = t - 640;  so = S_C3;  sho = SH_C3; }
        else              { src = bn_f;   nch = 128; c = t - 896;  so = S_F;   sho = SH_F;  }
        float g = src[c], b = src[nch + c], m = src[2 * nch + c], v = src[3 * nch + c];
        float s = g * rsqrtf(v + 1e-3f);
        wsf[so + c]  = s;
        wsf[sho + c] = b - m * s;
    }
    __syncthreads();
    // ---- pf collapse: parallel 4-way over c-chunks, LDS reduce ----
    {
        __shared__ float4 red[4][64];
        const int o = tid & 63, part = tid >> 6;
        float m0 = 0.f, m1 = 0.f, m2 = 0.f, cc = 0.f;
        for (int c = part * 16; c < part * 16 + 16; ++c) {
            float s1 = wsf[S_PF1 + c], t1 = wsf[SH_PF1 + c];
            float d1 = s1 * bpf1[c] + t1;
            float w2 = Wpf2[c * 64 + o];
            m0 += Wpf1[0 * 64 + c] * s1 * w2;
            m1 += Wpf1[1 * 64 + c] * s1 * w2;
            m2 += Wpf1[2 * 64 + c] * s1 * w2;
            cc += d1 * w2;
        }
        red[part][o] = make_float4(m0, m1, m2, cc);
        __syncthreads();
        if (part == 0) {
            float4 p0 = red[0][o], p1 = red[1][o], p2 = red[2][o], p3 = red[3][o];
            float M0 = ((p0.x + p1.x) + p2.x) + p3.x;
            float M1 = ((p0.y + p1.y) + p2.y) + p3.y;
            float M2 = ((p0.z + p1.z) + p2.z) + p3.z;
            float CC = ((p0.w + p1.w) + p2.w) + p3.w;
            float s2 = wsf[S_PF2 + o], t2 = wsf[SH_PF2 + o];
            wsf[M_OFF + 0 * 64 + o] = M0 * s2;
            wsf[M_OFF + 1 * 64 + o] = M1 * s2;
            wsf[M_OFF + 2 * 64 + o] = M2 * s2;
            wsf[C0_OFF + o]         = CC * s2 + bpf2[o] * s2 + t2;
        }
    }
}

// ---------------------------------------------------------------------------
// Kernel 1 (FULLY FUSED knn + pipeline + pointwise): one wave = one point.
// Phase 1: exact KNN on half-distances (ordering == reference d2 ordering).
// Phase 2: stages A..H with packed-f32 math, LDS-broadcast X3.
// Phase 3: final 256->128 layer as a per-wave matvec: dw row staged in the
//   wave-private LDS slice (reusing xA), lane l computes channels 2l, 2l+1.
// ---------------------------------------------------------------------------
__global__ __launch_bounds__(256) void fused_kernel(
    const float4* __restrict__ pts, const float* __restrict__ inp,
    const float* __restrict__ Wc1,  const float* __restrict__ bc1,
    const float* __restrict__ Wc2,  const float* __restrict__ bc2,
    const float* __restrict__ Wc3,  const float* __restrict__ bc3,
    const float* __restrict__ Wdf,  const float* __restrict__ Wpw,
    const float* __restrict__ bf,   const float* __restrict__ wsf,
    float* __restrict__ out) {

    __shared__ float xA[4][256];
    __shared__ float xB[4][256];

    const int w   = threadIdx.x >> 6;
    const int l   = threadIdx.x & 63;
    const int wid = (blockIdx.x << 2) | w;    // query/point id 0..8191
    const int b   = wid >> 10;
    const int qi  = wid & 1023;
    const float4* bp = pts + ((size_t)b << 12);

    const float4 q = bp[qi];
    const float hq = q.w;                     // 0.5*qq

#define DIST2(P) __fsub_rn(__fadd_rn(hq, (P).w), \
    __fadd_rn(__fadd_rn(__fmul_rn(q.x, (P).x), __fmul_rn(q.y, (P).y)), \
              __fmul_rn(q.z, (P).z)))

    // issue upcoming candidate loads early so they overlap the bootstrap sort
    float4 p  = bp[l];
    float4 g1 = bp[64 + l];
    float4 g2 = bp[128 + l];
    float4 g3 = bp[192 + l];

    // ---- bootstrap: bitonic sort first 64 by (d2', idx) ascending
    float d = DIST2(p);
    int ii = l;
#pragma unroll
    for (int k = 2; k <= 64; k <<= 1) {
#pragma unroll
        for (int j = k >> 1; j > 0; j >>= 1) {
            float od = __shfl_xor(d, j);
            int   oi = __shfl_xor(ii, j);
            bool keepmin = (((l & k) == 0) == ((l & j) == 0));
            bool ol = (od < d) || (od == d && oi < ii);
            bool take = keepmin ? ol : !ol;
            if (take) { d = od; ii = oi; }
        }
    }
    float bd = d;      // lane s (<32): s-th smallest
    int   bi = ii;
    float kth = rlf(bd, 31);

#define INS_LOOP(MV, D2V, BASE)                                        \
    if (MV) {                                                          \
        do {                                                           \
            int c = (int)__builtin_ctzll(MV); MV &= MV - 1;            \
            float dc = rlf(D2V, c);                                    \
            int   ic = (BASE) + c;                                     \
            float prev  = dpp_shr1_ninf(bd);                           \
            int   previ = dpp_shr1_i(bi);                              \
            bool c1 = (bd > dc);                                       \
            bool c2 = (prev > dc);                                     \
            bd = fminf(bd, fmaxf(prev, dc));                           \
            bi = c1 ? (c2 ? previ : ic) : bi;                          \
        } while (MV);                                                  \
        kth = rlf(bd, 31);                                             \
    }

    {
        float d2 = DIST2(g1);
        unsigned long long m = __ballot(d2 < kth);
        INS_LOOP(m, d2, 64);
    }
    for (int j0 = 128; j0 < NIN_; j0 += 128) {
        float4 pa = g2, pb = g3;
        int jn = j0 + 128;
        if (jn < NIN_) { g2 = bp[jn + l]; g3 = bp[jn + 64 + l]; }
        float d2a = DIST2(pa);
        unsigned long long ma = __ballot(d2a < kth);
        INS_LOOP(ma, d2a, j0);
        float d2b = DIST2(pb);
        unsigned long long mb = __ballot(d2b < kth);
        INS_LOOP(mb, d2b, j0 + 64);
    }
#undef INS_LOOP
#undef DIST2

    // ======== Phase 2: per-point pipeline (packed f32 math) ========
    const float* brow = inp + (size_t)b * NIN_ * CH_;
    const float q0 = q.x, q1 = q.y, q2 = q.z;

    // ---- xyz gather: ONE load instr. lanes 0..47: k = l/3, d = l%3.
    float pd;
    {
        int k3 = (l * 21846) >> 16;          // l/3 for l < 48
        k3 = (k3 > 15) ? 15 : k3;
        int d3 = l - ((k3 << 1) + k3);
        d3 = (d3 > 2) ? 2 : d3;
        int nbl = __shfl(bi, k3 << 1);       // neighbor index at rank 2*k3
        float v = 0.f;
        if (l < 48) v = brow[(size_t)nbl * CH_ + d3];
        float qv = (d3 == 0) ? q0 : ((d3 == 1) ? q1 : q2);
        pd = v - qv;
    }

    // ---- Stage D: x1[o] = BN(elu(pnb48 . Wc1 + bc1)),  o = 4l+r
    {
        f4 acc = *reinterpret_cast<const f4*>(bc1 + 4 * l);
#pragma unroll 4
        for (int t4 = 0; t4 < 12; ++t4) {
            const float* wb = Wc1 + (size_t)(t4 * 4) * 256 + 4 * l;
            f4 w0 = *reinterpret_cast<const f4*>(wb);
            f4 w1 = *reinterpret_cast<const f4*>(wb + 256);
            f4 w2 = *reinterpret_cast<const f4*>(wb + 512);
            f4 w3 = *reinterpret_cast<const f4*>(wb + 768);
            float p0 = rlf(pd, 4 * t4 + 0);
            float p1 = rlf(pd, 4 * t4 + 1);
            float p2 = rlf(pd, 4 * t4 + 2);
            float p3 = rlf(pd, 4 * t4 + 3);
            acc += p0 * w0 + p1 * w1 + p2 * w2 + p3 * w3;
        }
        f4 sc = *reinterpret_cast<const f4*>(wsf + S_C1 + 4 * l);
        f4 sh = *reinterpret_cast<const f4*>(wsf + SH_C1 + 4 * l);
        f4 r;
        r.x = sc.x * eluf(acc.x) + sh.x;
        r.y = sc.y * eluf(acc.y) + sh.y;
        r.z = sc.z * eluf(acc.z) + sh.z;
        r.w = sc.w * eluf(acc.w) + sh.w;
        *reinterpret_cast<f4*>(&xA[w][4 * l]) = r;
    }

    // ---- Stage E: x2[o] = BN(elu(sum_w x1[w][c]*Wc2[w][o])),  c = l>>2
    {
        f4 acc = *reinterpret_cast<const f4*>(bc2 + 4 * l);
        const int csel = l >> 2;
#pragma unroll 8
        for (int w16 = 0; w16 < 16; ++w16) {
            float xs = xA[w][w16 * 16 + csel];
            f4 w4 = *reinterpret_cast<const f4*>(Wc2 + (size_t)w16 * 256 + 4 * l);
            acc += xs * w4;
        }
        f4 sc = *reinterpret_cast<const f4*>(wsf + S_C2 + 4 * l);
        f4 sh = *reinterpret_cast<const f4*>(wsf + SH_C2 + 4 * l);
        f4 r;
        r.x = sc.x * eluf(acc.x) + sh.x;
        r.y = sc.y * eluf(acc.y) + sh.y;
        r.z = sc.z * eluf(acc.z) + sh.z;
        r.w = sc.w * eluf(acc.w) + sh.w;
        *reinterpret_cast<f4*>(&xB[w][4 * l]) = r;
    }

    // ---- Stage F: x3 -> straight into LDS (xA reused) for broadcast reads
    {
        f4 acc = *reinterpret_cast<const f4*>(bc3 + 4 * l);
        const int csel = l >> 2;
#pragma unroll 8
        for (int w16 = 0; w16 < 16; ++w16) {
            float xs = xB[w][w16 * 16 + csel];
            f4 w4 = *reinterpret_cast<const f4*>(Wc3 + (size_t)w16 * 256 + 4 * l);
            acc += xs * w4;
        }
        f4 sc = *reinterpret_cast<const f4*>(wsf + S_C3 + 4 * l);
        f4 sh = *reinterpret_cast<const f4*>(wsf + SH_C3 + 4 * l);
        f4 r;
        r.x = sc.x * eluf(acc.x) + sh.x;
        r.y = sc.y * eluf(acc.y) + sh.y;
        r.z = sc.z * eluf(acc.z) + sh.z;
        r.w = sc.w * eluf(acc.w) + sh.w;
        *reinterpret_cast<f4*>(&xA[w][4 * l]) = r;   // X3 element o = 4l+r
    }

    // ---- hf[k] = (h2[k], fnb[k]) pairs for packed G+H
    f2 hf[16];
    {
        const float Mw0 = wsf[M_OFF + l];
        const float Mw1 = wsf[M_OFF + 64 + l];
        const float Mw2 = wsf[M_OFF + 128 + l];
        const float cc0 = wsf[C0_OFF + l];
#pragma unroll
        for (int k = 0; k < 16; ++k) {
            int nbs = rli(bi, 2 * k);
            float fv = brow[(size_t)nbs * CH_ + 3 + l];
            float s0 = rlf(pd, 3 * k), s1 = rlf(pd, 3 * k + 1), s2 = rlf(pd, 3 * k + 2);
            float hv = fmaf(s0, Mw0, fmaf(s1, Mw1, fmaf(s2, Mw2, cc0)));
            f2 t; t.x = hv; t.y = fv;
            hf[k] = t;
        }
    }

    // ---- Stage G+H fused (packed): X3 rows via LDS broadcast b128 reads
    f2 dlo; dlo.x = 0.f; dlo.y = 0.f;
    f2 dhi = dlo;
#pragma unroll 4
    for (int i = 0; i < 16; ++i) {
        const f4* xr = reinterpret_cast<const f4*>(&xA[w][i * 16]);
        f4 x0 = xr[0], x1 = xr[1], x2 = xr[2], x3v = xr[3];
        f2 fab = x0.x * hf[0]  + x0.y * hf[1]  + x0.z * hf[2]  + x0.w * hf[3]
               + x1.x * hf[4]  + x1.y * hf[5]  + x1.z * hf[6]  + x1.w * hf[7]
               + x2.x * hf[8]  + x2.y * hf[9]  + x2.z * hf[10] + x2.w * hf[11]
               + x3v.x * hf[12]+ x3v.y * hf[13]+ x3v.z * hf[14]+ x3v.w * hf[15];
        const float* wr = Wdf + (size_t)i * 256;
        f2 wlo = *reinterpret_cast<const f2*>(wr + 2 * l);
        f2 whi = *reinterpret_cast<const f2*>(wr + 128 + 2 * l);
        dlo += fab.x * wlo;
        dhi += fab.y * whi;
    }

    // ======== Phase 3: pointwise layer in-wave ========
    // stage dw row into the wave-private LDS slice (in-order, no barrier)
    *reinterpret_cast<f2*>(&xA[w][2 * l])       = dlo;   // dw[2l], dw[2l+1]
    *reinterpret_cast<f2*>(&xA[w][128 + 2 * l]) = dhi;   // dw[128+2l], dw[129+2l]

    // lane l computes output channels n = 2l, 2l+1
    f2 o;
    o.x = bf[2 * l];
    o.y = bf[2 * l + 1];
#pragma unroll 8
    for (int k4 = 0; k4 < 64; ++k4) {
        f4 dv = *reinterpret_cast<const f4*>(&xA[w][4 * k4]);   // dw[4k..4k+3] broadcast
        const float* wp = Wpw + (size_t)(4 * k4) * 128 + 2 * l;
        f2 w0 = *reinterpret_cast<const f2*>(wp);
        f2 w1 = *reinterpret_cast<const f2*>(wp + 128);
        f2 w2 = *reinterpret_cast<const f2*>(wp + 256);
        f2 w3 = *reinterpret_cast<const f2*>(wp + 384);
        o += dv.x * w0 + dv.y * w1 + dv.z * w2 + dv.w * w3;
    }
    f2 sc = *reinterpret_cast<const f2*>(wsf + S_F + 2 * l);
    f2 sh = *reinterpret_cast<const f2*>(wsf + SH_F + 2 * l);
    f2 res;
    res.x = sc.x * eluf(o.x) + sh.x;
    res.y = sc.y * eluf(o.y) + sh.y;

    float* orow = out + (size_t)wid * 131;
    *reinterpret_cast<f2*>(orow + 3 + 2 * l) = res;
    if (l < 3) orow[l] = (l == 0) ? q0 : ((l == 1) ? q1 : q2);
}

// ---------------------------------------------------------------------------
extern "C" void kernel_launch(void* const* d_in, const int* in_sizes, int n_in,
                              void* d_out, int out_size, void* d_ws, size_t ws_size,
                              hipStream_t stream) {
    const float* inp   = (const float*)d_in[0];
    const float* Wpf1  = (const float*)d_in[1];
    const float* bpf1  = (const float*)d_in[2];
    const float* bnpf1 = (const float*)d_in[3];
    const float* Wpf2  = (const float*)d_in[4];
    const float* bpf2  = (const float*)d_in[5];
    const float* bnpf2 = (const float*)d_in[6];
    const float* Wc1   = (const float*)d_in[7];
    const float* bc1   = (const float*)d_in[8];
    const float* bnc1  = (const float*)d_in[9];
    const float* Wc2   = (const float*)d_in[10];
    const float* bc2   = (const float*)d_in[11];
    const float* bnc2  = (const float*)d_in[12];
    const float* Wc3   = (const float*)d_in[13];
    const float* bc3   = (const float*)d_in[14];
    const float* bnc3  = (const float*)d_in[15];
    const float* Wdf   = (const float*)d_in[16];
    const float* Wpw   = (const float*)d_in[17];
    const float* bf    = (const float*)d_in[18];
    const float* bnf   = (const float*)d_in[19];

    float*  wsf  = (float*)d_ws;
    float4* pts  = (float4*)((char*)d_ws + WS_PTS_OFF);
    float*  outp = (float*)d_out;

    hipLaunchKernelGGL(prep_kernel, dim3(129), dim3(256), 0, stream,
                       inp, pts, bnpf1, bnpf2, bnc1, bnc2, bnc3, bnf,
                       Wpf1, bpf1, Wpf2, bpf2, wsf);
    hipLaunchKernelGGL(fused_kernel, dim3((B_ * P_) / 4), dim3(256), 0, stream,
                       pts, inp, Wc1, bc1, Wc2, bc2, Wc3, bc3, Wdf, Wpw,
                       bf, wsf, outp);
}

// Round 12
// 102.617 us; speedup vs baseline: 1.2775x; 1.2775x over previous
//
#include <hip/hip_runtime.h>
#include <math.h>

#define B_    8
#define NIN_  4096
#define P_    1024
#define K_    16
#define F_    64
#define CH_   67      // 3 + F
#define CPF_  64
#define CIN_  128
#define C_    128

// ---- ws float-offset layout ----
#define S_PF1  0
#define SH_PF1 64
#define S_PF2  128
#define SH_PF2 192
#define S_C1   256
#define SH_C1  512
#define S_C2   768
#define SH_C2  1024
#define S_C3   1280
#define SH_C3  1536
#define S_F    1792
#define SH_F   1920
#define M_OFF  2048     // fused pf matrix 3x64
#define C0_OFF 2240     // fused pf bias 64

// byte offsets in ws
#define WS_PTS_OFF  16384
#define WS_DWL_OFF  (WS_PTS_OFF + B_ * NIN_ * 16)          // 540672

typedef float f2 __attribute__((ext_vector_type(2)));
typedef float f4 __attribute__((ext_vector_type(4)));

__device__ __forceinline__ float rlf(float x, int l) {
    return __int_as_float(__builtin_amdgcn_readlane(__float_as_int(x), l));
}
__device__ __forceinline__ int rli(int x, int l) {
    return __builtin_amdgcn_readlane(x, l);
}
__device__ __forceinline__ float eluf(float z) {
    return z > 0.f ? z : (__expf(z) - 1.0f);
}
// whole-wave shift-right-by-1 via DPP (VALU). lane0 receives -inf.
__device__ __forceinline__ float dpp_shr1_ninf(float x) {
    return __int_as_float(__builtin_amdgcn_update_dpp(
        (int)0xFF800000, __float_as_int(x), 0x138, 0xF, 0xF, false));
}
// lane0 keeps old value (don't-care for index path)
__device__ __forceinline__ int dpp_shr1_i(int x) {
    return __builtin_amdgcn_update_dpp(x, x, 0x138, 0xF, 0xF, false);
}

// ---------------------------------------------------------------------------
// Kernel 0 (fused prep): blocks 0..127 pack xyz + 0.5*|p|^2 into float4;
// block 128 folds BN params and collapses pf1+pf2 into a 3->64 affine.
// ---------------------------------------------------------------------------
__global__ __launch_bounds__(256) void prep_kernel(
    const float* __restrict__ inp, float4* __restrict__ pts,
    const float* __restrict__ bn_pf1, const float* __restrict__ bn_pf2,
    const float* __restrict__ bn_c1,  const float* __restrict__ bn_c2,
    const float* __restrict__ bn_c3,  const float* __restrict__ bn_f,
    const float* __restrict__ Wpf1,   const float* __restrict__ bpf1,
    const float* __restrict__ Wpf2,   const float* __restrict__ bpf2,
    float* __restrict__ wsf) {
    const int tid = threadIdx.x;
    if (blockIdx.x < 128) {
        int i = blockIdx.x * 256 + tid;
        const float* r = inp + (size_t)i * CH_;
        float x = r[0], y = r[1], z = r[2];
        float pp = __fadd_rn(__fadd_rn(__fmul_rn(x, x), __fmul_rn(y, y)),
                             __fmul_rn(z, z));
        pts[i] = make_float4(x, y, z, __fmul_rn(0.5f, pp));
        return;
    }
#pragma unroll
    for (int it = 0; it < 4; ++it) {
        int t = it * 256 + tid;
        const float* src; int nch, c, so, sho;
        if (t < 64)       { src = bn_pf1; nch = 64;  c = t;        so = S_PF1; sho = SH_PF1; }
        else if (t < 128) { src = bn_pf2; nch = 64;  c = t - 64;   so = S_PF2; sho = SH_PF2; }
        else if (t < 384) { src = bn_c1;  nch = 256; c = t - 128;  so = S_C1;  sho = SH_C1; }
        else if (t < 640) { src = bn_c2;  nch = 256; c = t - 384;  so = S_C2;  sho = SH_C2; }
        else if (t < 896) { src = bn_c3;  nch = 256; c = t - 640;  so = S_C3;  sho = SH_C3; }
        else              { src = bn_f;   nch = 128; c = t - 896;  so = S_F;   sho = SH_F;  }
        float g = src[c], b = src[nch + c], m = src[2 * nch + c], v = src[3 * nch + c];
        float s = g * rsqrtf(v + 1e-3f);
        wsf[so + c]  = s;
        wsf[sho + c] = b - m * s;
    }
    __syncthreads();
    // ---- pf collapse: parallel 4-way over c-chunks, LDS reduce ----
    {
        __shared__ float4 red[4][64];
        const int o = tid & 63, part = tid >> 6;
        float m0 = 0.f, m1 = 0.f, m2 = 0.f, cc = 0.f;
        for (int c = part * 16; c < part * 16 + 16; ++c) {
            float s1 = wsf[S_PF1 + c], t1 = wsf[SH_PF1 + c];
            float d1 = s1 * bpf1[c] + t1;
            float w2 = Wpf2[c * 64 + o];
            m0 += Wpf1[0 * 64 + c] * s1 * w2;
            m1 += Wpf1[1 * 64 + c] * s1 * w2;
            m2 += Wpf1[2 * 64 + c] * s1 * w2;
            cc += d1 * w2;
        }
        red[part][o] = make_float4(m0, m1, m2, cc);
        __syncthreads();
        if (part == 0) {
            float4 p0 = red[0][o], p1 = red[1][o], p2 = red[2][o], p3 = red[3][o];
            float M0 = ((p0.x + p1.x) + p2.x) + p3.x;
            float M1 = ((p0.y + p1.y) + p2.y) + p3.y;
            float M2 = ((p0.z + p1.z) + p2.z) + p3.z;
            float CC = ((p0.w + p1.w) + p2.w) + p3.w;
            float s2 = wsf[S_PF2 + o], t2 = wsf[SH_PF2 + o];
            wsf[M_OFF + 0 * 64 + o] = M0 * s2;
            wsf[M_OFF + 1 * 64 + o] = M1 * s2;
            wsf[M_OFF + 2 * 64 + o] = M2 * s2;
            wsf[C0_OFF + o]         = CC * s2 + bpf2[o] * s2 + t2;
        }
    }
}

// ---------------------------------------------------------------------------
// Kernel 1 (FUSED knn + pipeline): one wave = one query = one point.
// Phase 1: exact KNN on half-distances d2' = (hq + hp) - e; d2' = 0.5*d2
//   exactly (power-of-2), so ordering AND ties match the reference.
//   Strict-shift stable insertion via DPP; sorted top-32 across lanes 0..31.
// Phase 2: pipeline stages A..H, packed-f32 math, LDS-broadcast X3.
// Writes the dw row [8192][256] for the tiled pw GEMM (Wpw amortization).
// ---------------------------------------------------------------------------
__global__ __launch_bounds__(256) void fused_kernel(
    const float4* __restrict__ pts, const float* __restrict__ inp,
    const float* __restrict__ Wc1,  const float* __restrict__ bc1,
    const float* __restrict__ Wc2,  const float* __restrict__ bc2,
    const float* __restrict__ Wc3,  const float* __restrict__ bc3,
    const float* __restrict__ Wdf,  const float* __restrict__ wsf,
    float* __restrict__ dwl, float* __restrict__ out) {

    __shared__ float xA[4][256];
    __shared__ float xB[4][256];

    const int w   = threadIdx.x >> 6;
    const int l   = threadIdx.x & 63;
    const int wid = (blockIdx.x << 2) | w;    // query/point id 0..8191
    const int b   = wid >> 10;
    const int qi  = wid & 1023;
    const float4* bp = pts + ((size_t)b << 12);

    const float4 q = bp[qi];
    const float hq = q.w;                     // 0.5*qq

#define DIST2(P) __fsub_rn(__fadd_rn(hq, (P).w), \
    __fadd_rn(__fadd_rn(__fmul_rn(q.x, (P).x), __fmul_rn(q.y, (P).y)), \
              __fmul_rn(q.z, (P).z)))

    // issue upcoming candidate loads early so they overlap the bootstrap sort
    float4 p  = bp[l];
    float4 g1 = bp[64 + l];
    float4 g2 = bp[128 + l];
    float4 g3 = bp[192 + l];

    // ---- bootstrap: bitonic sort first 64 by (d2', idx) ascending
    float d = DIST2(p);
    int ii = l;
#pragma unroll
    for (int k = 2; k <= 64; k <<= 1) {
#pragma unroll
        for (int j = k >> 1; j > 0; j >>= 1) {
            float od = __shfl_xor(d, j);
            int   oi = __shfl_xor(ii, j);
            bool keepmin = (((l & k) == 0) == ((l & j) == 0));
            bool ol = (od < d) || (od == d && oi < ii);
            bool take = keepmin ? ol : !ol;
            if (take) { d = od; ii = oi; }
        }
    }
    float bd = d;      // lane s (<32): s-th smallest
    int   bi = ii;
    float kth = rlf(bd, 31);

#define INS_LOOP(MV, D2V, BASE)                                        \
    if (MV) {                                                          \
        do {                                                           \
            int c = (int)__builtin_ctzll(MV); MV &= MV - 1;            \
            float dc = rlf(D2V, c);                                    \
            int   ic = (BASE) + c;                                     \
            float prev  = dpp_shr1_ninf(bd);                           \
            int   previ = dpp_shr1_i(bi);                              \
            bool c1 = (bd > dc);                                       \
            bool c2 = (prev > dc);                                     \
            bd = fminf(bd, fmaxf(prev, dc));                           \
            bi = c1 ? (c2 ? previ : ic) : bi;                          \
        } while (MV);                                                  \
        kth = rlf(bd, 31);                                             \
    }

    {
        float d2 = DIST2(g1);
        unsigned long long m = __ballot(d2 < kth);
        INS_LOOP(m, d2, 64);
    }
    for (int j0 = 128; j0 < NIN_; j0 += 128) {
        float4 pa = g2, pb = g3;
        int jn = j0 + 128;
        if (jn < NIN_) { g2 = bp[jn + l]; g3 = bp[jn + 64 + l]; }
        float d2a = DIST2(pa);
        unsigned long long ma = __ballot(d2a < kth);
        INS_LOOP(ma, d2a, j0);
        float d2b = DIST2(pb);
        unsigned long long mb = __ballot(d2b < kth);
        INS_LOOP(mb, d2b, j0 + 64);
    }
#undef INS_LOOP
#undef DIST2

    // ======== Phase 2: per-point pipeline (packed f32 math) ========
    const float* brow = inp + (size_t)b * NIN_ * CH_;
    const float q0 = q.x, q1 = q.y, q2 = q.z;

    // ---- xyz gather: ONE load instr. lanes 0..47: k = l/3, d = l%3.
    float pd;
    {
        int k3 = (l * 21846) >> 16;          // l/3 for l < 48
        k3 = (k3 > 15) ? 15 : k3;
        int d3 = l - ((k3 << 1) + k3);
        d3 = (d3 > 2) ? 2 : d3;
        int nbl = __shfl(bi, k3 << 1);       // neighbor index at rank 2*k3
        float v = 0.f;
        if (l < 48) v = brow[(size_t)nbl * CH_ + d3];
        float qv = (d3 == 0) ? q0 : ((d3 == 1) ? q1 : q2);
        pd = v - qv;
    }

    // ---- Stage D: x1[o] = BN(elu(pnb48 . Wc1 + bc1)),  o = 4l+r
    {
        f4 acc = *reinterpret_cast<const f4*>(bc1 + 4 * l);
#pragma unroll 4
        for (int t4 = 0; t4 < 12; ++t4) {
            const float* wb = Wc1 + (size_t)(t4 * 4) * 256 + 4 * l;
            f4 w0 = *reinterpret_cast<const f4*>(wb);
            f4 w1 = *reinterpret_cast<const f4*>(wb + 256);
            f4 w2 = *reinterpret_cast<const f4*>(wb + 512);
            f4 w3 = *reinterpret_cast<const f4*>(wb + 768);
            float p0 = rlf(pd, 4 * t4 + 0);
            float p1 = rlf(pd, 4 * t4 + 1);
            float p2 = rlf(pd, 4 * t4 + 2);
            float p3 = rlf(pd, 4 * t4 + 3);
            acc += p0 * w0 + p1 * w1 + p2 * w2 + p3 * w3;
        }
        f4 sc = *reinterpret_cast<const f4*>(wsf + S_C1 + 4 * l);
        f4 sh = *reinterpret_cast<const f4*>(wsf + SH_C1 + 4 * l);
        f4 r;
        r.x = sc.x * eluf(acc.x) + sh.x;
        r.y = sc.y * eluf(acc.y) + sh.y;
        r.z = sc.z * eluf(acc.z) + sh.z;
        r.w = sc.w * eluf(acc.w) + sh.w;
        *reinterpret_cast<f4*>(&xA[w][4 * l]) = r;
    }

    // ---- Stage E: x2[o] = BN(elu(sum_w x1[w][c]*Wc2[w][o])),  c = l>>2
    {
        f4 acc = *reinterpret_cast<const f4*>(bc2 + 4 * l);
        const int csel = l >> 2;
#pragma unroll 8
        for (int w16 = 0; w16 < 16; ++w16) {
            float xs = xA[w][w16 * 16 + csel];
            f4 w4 = *reinterpret_cast<const f4*>(Wc2 + (size_t)w16 * 256 + 4 * l);
            acc += xs * w4;
        }
        f4 sc = *reinterpret_cast<const f4*>(wsf + S_C2 + 4 * l);
        f4 sh = *reinterpret_cast<const f4*>(wsf + SH_C2 + 4 * l);
        f4 r;
        r.x = sc.x * eluf(acc.x) + sh.x;
        r.y = sc.y * eluf(acc.y) + sh.y;
        r.z = sc.z * eluf(acc.z) + sh.z;
        r.w = sc.w * eluf(acc.w) + sh.w;
        *reinterpret_cast<f4*>(&xB[w][4 * l]) = r;
    }

    // ---- Stage F: x3 -> straight into LDS (xA reused) for broadcast reads
    {
        f4 acc = *reinterpret_cast<const f4*>(bc3 + 4 * l);
        const int csel = l >> 2;
#pragma unroll 8
        for (int w16 = 0; w16 < 16; ++w16) {
            float xs = xB[w][w16 * 16 + csel];
            f4 w4 = *reinterpret_cast<const f4*>(Wc3 + (size_t)w16 * 256 + 4 * l);
            acc += xs * w4;
        }
        f4 sc = *reinterpret_cast<const f4*>(wsf + S_C3 + 4 * l);
        f4 sh = *reinterpret_cast<const f4*>(wsf + SH_C3 + 4 * l);
        f4 r;
        r.x = sc.x * eluf(acc.x) + sh.x;
        r.y = sc.y * eluf(acc.y) + sh.y;
        r.z = sc.z * eluf(acc.z) + sh.z;
        r.w = sc.w * eluf(acc.w) + sh.w;
        *reinterpret_cast<f4*>(&xA[w][4 * l]) = r;   // X3 element o = 4l+r
    }

    // ---- hf[k] = (h2[k], fnb[k]) pairs for packed G+H
    f2 hf[16];
    {
        const float Mw0 = wsf[M_OFF + l];
        const float Mw1 = wsf[M_OFF + 64 + l];
        const float Mw2 = wsf[M_OFF + 128 + l];
        const float cc0 = wsf[C0_OFF + l];
#pragma unroll
        for (int k = 0; k < 16; ++k) {
            int nbs = rli(bi, 2 * k);
            float fv = brow[(size_t)nbs * CH_ + 3 + l];
            float s0 = rlf(pd, 3 * k), s1 = rlf(pd, 3 * k + 1), s2 = rlf(pd, 3 * k + 2);
            float hv = fmaf(s0, Mw0, fmaf(s1, Mw1, fmaf(s2, Mw2, cc0)));
            f2 t; t.x = hv; t.y = fv;
            hf[k] = t;
        }
    }

    // ---- Stage G+H fused (packed): X3 rows via LDS broadcast b128 reads
    f2 dlo; dlo.x = 0.f; dlo.y = 0.f;
    f2 dhi = dlo;
#pragma unroll 4
    for (int i = 0; i < 16; ++i) {
        const f4* xr = reinterpret_cast<const f4*>(&xA[w][i * 16]);
        f4 x0 = xr[0], x1 = xr[1], x2 = xr[2], x3v = xr[3];
        f2 fab = x0.x * hf[0]  + x0.y * hf[1]  + x0.z * hf[2]  + x0.w * hf[3]
               + x1.x * hf[4]  + x1.y * hf[5]  + x1.z * hf[6]  + x1.w * hf[7]
               + x2.x * hf[8]  + x2.y * hf[9]  + x2.z * hf[10] + x2.w * hf[11]
               + x3v.x * hf[12]+ x3v.y * hf[13]+ x3v.z * hf[14]+ x3v.w * hf[15];
        const float* wr = Wdf + (size_t)i * 256;
        f2 wlo = *reinterpret_cast<const f2*>(wr + 2 * l);
        f2 whi = *reinterpret_cast<const f2*>(wr + 128 + 2 * l);
        dlo += fab.x * wlo;
        dhi += fab.y * whi;
    }
    float* drow = dwl + (size_t)wid * 256;
    *reinterpret_cast<f2*>(drow + 2 * l)       = dlo;
    *reinterpret_cast<f2*>(drow + 128 + 2 * l) = dhi;

    if (l < 3) out[(size_t)wid * 131 + l] = (l == 0) ? q0 : ((l == 1) ? q1 : q2);
}

// ---------------------------------------------------------------------------
// Kernel 2: final pointwise layer as tiled f32 GEMM: M=8192 K=256 N=128.
// Mtile=32 per block (Wpw amortized over 32 rows), thread tile 4m x 4n.
// ---------------------------------------------------------------------------
__global__ __launch_bounds__(256) void pw_kernel(const float* __restrict__ dwl,
                                                 const float* __restrict__ Wpw,
                                                 const float* __restrict__ bf,
                                                 const float* __restrict__ wsf,
                                                 float* __restrict__ out) {
    __shared__ float As[32][256];
    const int tid = threadIdx.x;
    const int m0  = blockIdx.x * 32;

#pragma unroll
    for (int i = 0; i < 8; ++i) {
        int fi  = i * 1024 + tid * 4;
        int row = fi >> 8, col = fi & 255;
        *reinterpret_cast<float4*>(&As[row][col]) =
            *reinterpret_cast<const float4*>(dwl + (size_t)(m0 + row) * 256 + col);
    }
    __syncthreads();

    const int mq = tid >> 5;          // 8 m-quads
    const int nq = tid & 31;          // 32 n-quads
    f4 acc[4];
#pragma unroll
    for (int mi = 0; mi < 4; ++mi) { acc[mi].x = 0.f; acc[mi].y = 0.f; acc[mi].z = 0.f; acc[mi].w = 0.f; }

#pragma unroll 4
    for (int k4 = 0; k4 < 64; ++k4) {
        f4 a[4], bw[4];
#pragma unroll
        for (int mi = 0; mi < 4; ++mi)
            a[mi] = *reinterpret_cast<const f4*>(&As[mq * 4 + mi][k4 * 4]);
#pragma unroll
        for (int ki = 0; ki < 4; ++ki)
            bw[ki] = *reinterpret_cast<const f4*>(Wpw + (size_t)(k4 * 4 + ki) * 128 + nq * 4);
#pragma unroll
        for (int mi = 0; mi < 4; ++mi) {
            acc[mi] += a[mi].x * bw[0] + a[mi].y * bw[1] + a[mi].z * bw[2] + a[mi].w * bw[3];
        }
    }

    f4 b4  = *reinterpret_cast<const f4*>(bf + nq * 4);
    f4 sc4 = *reinterpret_cast<const f4*>(wsf + S_F + nq * 4);
    f4 sh4 = *reinterpret_cast<const f4*>(wsf + SH_F + nq * 4);
#pragma unroll
    for (int mi = 0; mi < 4; ++mi) {
        const int m = m0 + mq * 4 + mi;
        float* orow = out + (size_t)m * 131 + 3 + nq * 4;
        orow[0] = sc4.x * eluf(acc[mi].x + b4.x) + sh4.x;
        orow[1] = sc4.y * eluf(acc[mi].y + b4.y) + sh4.y;
        orow[2] = sc4.z * eluf(acc[mi].z + b4.z) + sh4.z;
        orow[3] = sc4.w * eluf(acc[mi].w + b4.w) + sh4.w;
    }
}

// ---------------------------------------------------------------------------
extern "C" void kernel_launch(void* const* d_in, const int* in_sizes, int n_in,
                              void* d_out, int out_size, void* d_ws, size_t ws_size,
                              hipStream_t stream) {
    const float* inp   = (const float*)d_in[0];
    const float* Wpf1  = (const float*)d_in[1];
    const float* bpf1  = (const float*)d_in[2];
    const float* bnpf1 = (const float*)d_in[3];
    const float* Wpf2  = (const float*)d_in[4];
    const float* bpf2  = (const float*)d_in[5];
    const float* bnpf2 = (const float*)d_in[6];
    const float* Wc1   = (const float*)d_in[7];
    const float* bc1   = (const float*)d_in[8];
    const float* bnc1  = (const float*)d_in[9];
    const float* Wc2   = (const float*)d_in[10];
    const float* bc2   = (const float*)d_in[11];
    const float* bnc2  = (const float*)d_in[12];
    const float* Wc3   = (const float*)d_in[13];
    const float* bc3   = (const float*)d_in[14];
    const float* bnc3  = (const float*)d_in[15];
    const float* Wdf   = (const float*)d_in[16];
    const float* Wpw   = (const float*)d_in[17];
    const float* bf    = (const float*)d_in[18];
    const float* bnf   = (const float*)d_in[19];

    float*  wsf  = (float*)d_ws;
    float4* pts  = (float4*)((char*)d_ws + WS_PTS_OFF);
    float*  dwl  = (float*)((char*)d_ws + WS_DWL_OFF);
    float*  outp = (float*)d_out;

    hipLaunchKernelGGL(prep_kernel, dim3(129), dim3(256), 0, stream,
                       inp, pts, bnpf1, bnpf2, bnc1, bnc2, bnc3, bnf,
                       Wpf1, bpf1, Wpf2, bpf2, wsf);
    hipLaunchKernelGGL(fused_kernel, dim3((B_ * P_) / 4), dim3(256), 0, stream,
                       pts, inp, Wc1, bc1, Wc2, bc2, Wc3, bc3, Wdf, wsf,
                       dwl, outp);
    hipLaunchKernelGGL(pw_kernel, dim3((B_ * P_) / 32), dim3(256), 0, stream,
                       dwl, Wpw, bf, wsf, outp);
}